// Round 9
// baseline (279.092 us; speedup 1.0000x reference)
//
#include <hip/hip_runtime.h>
#include <math.h>

#define NB 2
#define NQ 16384        // 32*512 downsampled points per batch
#define IN_H 64
#define IN_W 2048
#define BIG 1e30f
#define NQT (NB * NQ)
#define NCH 8           // target chunks per batch
#define CHT 2048        // targets per chunk = 64 MFMA tiles
#define PLN ((size_t)IN_H * IN_W)

typedef __bf16 bf16x8 __attribute__((ext_vector_type(8)));
typedef float f32x16 __attribute__((ext_vector_type(16)));

__device__ inline float med3(float a, float b, float c) {
    return __builtin_amdgcn_fmed3f(a, b, c);
}
// branchless sorted-insert of v into b0<=b1<=b2 (3 VALU)
#define INSERT3(B0, B1, B2, V)                    \
    do { float _v = (V);                          \
         (B2) = med3((B1), (B2), _v);             \
         (B1) = med3((B0), (B1), _v);             \
         (B0) = fminf((B0), _v); } while (0)

union PK { __bf16 h[8]; uint4 u; };

// ---------------------------------------------------------------------------
// pack_kernel (R6-verified): (a) compensated bf16 A-fragments for
// mfma_f32_32x32x16_bf16 — lane holds A[row=lane&31][k=(lane>>5)*8+j];
// -2 folded into t, ||t||^2 hi/lo, BIG sentinel for invalid targets;
// (b) compact fp32 float4 (x,y,z,||t||^2) for the exact pass-2 recompute
// (invalid -> xyz=0, w=1e20 so sqrt=1e10 = reference INVALID_DIST);
// (c) zeroes the 2 KB control region (accum/done/qtcnt) — no memset node.
// ---------------------------------------------------------------------------
__global__ __launch_bounds__(256) void pack_kernel(
    const float* __restrict__ tgt_pc,   // [B,3,64,2048]
    uint4* __restrict__ packed,
    float4* __restrict__ tgt4,
    int* __restrict__ zws)              // 2 KB control region
{
    if (blockIdx.x == 0) { zws[threadIdx.x] = 0; zws[256 + threadIdx.x] = 0; }

    int gid = blockIdx.x * 256 + threadIdx.x;   // [0, NB*NQ)
    int b = gid >> 14, t = gid & (NQ - 1);
    int oh = t >> 9, ow = t & 511;
    size_t base = ((size_t)(b * 3) * IN_H + oh * 2) * IN_W + ow * 4;
    float x = tgt_pc[base], y = tgt_pc[base + PLN], z = tgt_pc[base + 2 * PLN];
    bool valid = (x != 0.f) || (y != 0.f) || (z != 0.f);
    float ntx = x * x + y * y + z * z;
    float nt = valid ? ntx : BIG;               // pass-1 sentinel
    float tx = valid ? -2.f * x : 0.f;
    float ty = valid ? -2.f * y : 0.f;
    float tz = valid ? -2.f * z : 0.f;

    __bf16 txh = (__bf16)tx, tyh = (__bf16)ty, tzh = (__bf16)tz;
    __bf16 txl = (__bf16)(tx - (float)txh);
    __bf16 tyl = (__bf16)(ty - (float)tyh);
    __bf16 tzl = (__bf16)(tz - (float)tzh);
    __bf16 nth = (__bf16)nt;
    __bf16 ntl = (__bf16)(nt - (float)nth);

    PK h0, h1;
    h0.h[0] = txh; h0.h[1] = tyh; h0.h[2] = tzh; h0.h[3] = txh;
    h0.h[4] = tyh; h0.h[5] = tzh; h0.h[6] = txl; h0.h[7] = tyl;
    h1.h[0] = tzl; h1.h[1] = nth; h1.h[2] = ntl; h1.h[3] = (__bf16)1.0f;
    h1.h[4] = (__bf16)1.0f; h1.h[5] = (__bf16)0.0f;
    h1.h[6] = (__bf16)0.0f; h1.h[7] = (__bf16)0.0f;

    int tile = t >> 5, m = t & 31;
    size_t o = (size_t)(b * 512 + tile) * 64 + m;   // uint4 units
    packed[o]      = h0.u;   // k0..7
    packed[o + 32] = h1.u;   // k8..15

    tgt4[gid] = make_float4(valid ? x : 0.f, valid ? y : 0.f,
                            valid ? z : 0.f, valid ? ntx : 1e20f);
}

// ---------------------------------------------------------------------------
// knn_mfma (R6 body + occupancy + fused merge):
// block = 128 queries (4 waves x 32, query col = lane&31) x one 2048-target
// chunk (64 tiles). grid = NB*NCH*128 = 2048 blocks ~ 8/CU (R6 was 4/CU at
// 28.5% occupancy — the diagnosed limiter). LDS: 2 x 8 KB double buffer
// (8 tiles/stage, 8 stages), coalesced pre-packed uint4 staging.
// Pass 1: per tile MFMA + min-tree(16) + idx-pack(6 bits) + INSERT3 ->
//         top-3 candidate tiles per lane (top-3 values provably live in the
//         3 smallest-min tiles of each lane's 16-row slice).
// Pass 2: exact fp32 recompute of 3x16 candidate rows from tgt4 (L2),
//         no divergence beyond the candidate gather (R7/R8's divergent
//         sub-stage loop is gone — this is the R6 form).
// Phase 3 (R7/R8-validated): partial stores -> fence -> last-of-8 block per
//         (b,qt) merges 24 trios, sqrt+clamp+masked reduce -> batch atomics;
//         last merger writes the scalar.
// ---------------------------------------------------------------------------
__global__ __launch_bounds__(256) void knn_mfma(
    const float* __restrict__ src_pc,   // [B,64,2048,3]
    const uint4* __restrict__ packed,
    const float4* __restrict__ tgt4,
    float* __restrict__ partial,        // [NCH*3][NQT] plane-major
    float* __restrict__ accum,          // {sum0,cnt0,sum1,cnt1}
    int* __restrict__ qtcnt,            // [NB*128]
    int* __restrict__ done_cnt,
    float* __restrict__ out)
{
    __shared__ uint4 lds[2][512];       // 2 x 8 KB
    __shared__ int winner;
    __shared__ float sd[4], sw4[4];

    const int tid = threadIdx.x;
    const int lane = tid & 63;
    const int wv = tid >> 6;
    const int half = lane >> 5;
    const int blk = blockIdx.x;
    const int qt = blk & 127;                   // 128 query tiles of 128
    const int chunk = (blk >> 7) & (NCH - 1);
    const int b = blk >> 10;
    const int n = lane & 31;
    const int q = qt * 128 + wv * 32 + n;

    // ---- query-side B fragment (col = lane&31, k = (lane>>5)*8 + j) ----
    size_t sbase = (((size_t)b * IN_H + (q >> 9) * 2) * IN_W + (q & 511) * 4) * 3;
    float sx = src_pc[sbase], sy = src_pc[sbase + 1], sz = src_pc[sbase + 2];
    float ns = sx * sx + sy * sy + sz * sz;
    __bf16 sxh = (__bf16)sx, syh = (__bf16)sy, szh = (__bf16)sz;
    __bf16 sxl = (__bf16)(sx - (float)sxh);
    __bf16 syl = (__bf16)(sy - (float)syh);
    __bf16 szl = (__bf16)(sz - (float)szh);
    __bf16 nsh = (__bf16)ns, nsl = (__bf16)(ns - (float)nsh);
    bf16x8 bq;
    if (half == 0) {
        bq[0] = sxh; bq[1] = syh; bq[2] = szh; bq[3] = sxl;
        bq[4] = syl; bq[5] = szl; bq[6] = sxh; bq[7] = syh;
    } else {
        bq[0] = szh; bq[1] = (__bf16)1.0f; bq[2] = (__bf16)1.0f; bq[3] = nsh;
        bq[4] = nsl; bq[5] = (__bf16)0.0f; bq[6] = (__bf16)0.0f; bq[7] = (__bf16)0.0f;
    }

    f32x16 zero;
    #pragma unroll
    for (int i = 0; i < 16; ++i) zero[i] = 0.f;

    float c0 = BIG, c1 = BIG, c2 = BIG;     // packed (tile-min | tile-idx)

    // this chunk's 64 tiles, 64 uint4 each
    const uint4* pkq = packed + (size_t)b * 32768 + (size_t)chunk * 4096;

    uint4 r[2];
    #pragma unroll
    for (int i = 0; i < 2; ++i) r[i] = pkq[tid + 256 * i];          // stage 0
    #pragma unroll
    for (int i = 0; i < 2; ++i) lds[0][tid + 256 * i] = r[i];
    __syncthreads();

    for (int s = 0; s < 8; ++s) {
        uint4 rn[2];
        if (s < 7) {
            const uint4* nsrc = pkq + (s + 1) * 512;
            #pragma unroll
            for (int i = 0; i < 2; ++i) rn[i] = nsrc[tid + 256 * i];
        }
        const uint4* buf = lds[s & 1];
        #pragma unroll 2
        for (int t = 0; t < 8; ++t) {
            bf16x8 af = __builtin_bit_cast(bf16x8, buf[t * 64 + lane]);
            f32x16 d = __builtin_amdgcn_mfma_f32_32x32x16_bf16(af, bq, zero, 0, 0, 0);
            float m0 = fminf(fminf(d[0], d[1]), fminf(d[2], d[3]));
            float m1 = fminf(fminf(d[4], d[5]), fminf(d[6], d[7]));
            float m2 = fminf(fminf(d[8], d[9]), fminf(d[10], d[11]));
            float m3 = fminf(fminf(d[12], d[13]), fminf(d[14], d[15]));
            float mm = fminf(fminf(m0, m1), fminf(m2, m3));
            unsigned u = (__float_as_uint(mm) & ~63u) | (unsigned)(s * 8 + t);
            INSERT3(c0, c1, c2, __uint_as_float(u));
        }
        if (s < 7) {
            #pragma unroll
            for (int i = 0; i < 2; ++i) lds[1 - (s & 1)][tid + 256 * i] = rn[i];
        }
        __syncthreads();
    }

    // ---- pass 2: exact fp32 recompute of 3 candidate tiles from L2 ----
    int ti0 = (int)(__float_as_uint(c0) & 63u);
    int ti1 = (int)(__float_as_uint(c1) & 63u);
    int ti2 = (int)(__float_as_uint(c2) & 63u);
    float e0 = BIG, e1 = BIG, e2 = BIG;
    const float4* t4b = tgt4 + (size_t)b * NQ + (size_t)chunk * CHT;
    #pragma unroll
    for (int i = 0; i < 3; ++i) {
        int ct = (i == 0) ? ti0 : (i == 1) ? ti1 : ti2;
        int tbase = ct * 32 + 4 * half;
        #pragma unroll 4
        for (int rr = 0; rr < 16; ++rr) {
            int row = (rr & 3) + 8 * (rr >> 2);
            float4 tv = t4b[tbase + row];
            float dot = sx * tv.x;
            dot = fmaf(sy, tv.y, dot);
            dot = fmaf(sz, tv.z, dot);
            float d2 = fmaf(-2.f, dot, ns + tv.w);
            INSERT3(e0, e1, e2, d2);
        }
    }

    // ---- phase 3: merge halves, store partials, last-block merge ----
    float f0 = __shfl_down(e0, 32, 64);
    float f1 = __shfl_down(e1, 32, 64);
    float f2 = __shfl_down(e2, 32, 64);
    if (half == 0) {
        INSERT3(e0, e1, e2, f0);
        INSERT3(e0, e1, e2, f1);
        INSERT3(e0, e1, e2, f2);
        int gq = b * NQ + q;
        partial[(chunk * 3 + 0) * NQT + gq] = e0;
        partial[(chunk * 3 + 1) * NQT + gq] = e1;
        partial[(chunk * 3 + 2) * NQT + gq] = e2;
    }
    __threadfence();            // release partial stores device-wide
    __syncthreads();
    if (tid == 0) {
        int rr = atomicAdd(&qtcnt[b * 128 + qt], 1);
        winner = (rr == NCH - 1) ? 1 : 0;
    }
    __syncthreads();
    if (!winner) return;
    __threadfence();            // acquire

    float dsum = 0.f, wcnt = 0.f;
    if (tid < 128) {
        int gq2 = b * NQ + qt * 128 + tid;
        float b0 = BIG, b1 = BIG, b2 = BIG;
        #pragma unroll
        for (int c = 0; c < NCH * 3; ++c)
            INSERT3(b0, b1, b2, partial[c * NQT + gq2]);
        int qq = qt * 128 + tid;
        size_t sb2 = (((size_t)b * IN_H + (qq >> 9) * 2) * IN_W + (qq & 511) * 4) * 3;
        float x = src_pc[sb2], y = src_pc[sb2 + 1], z = src_pc[sb2 + 2];
        wcnt = ((x != 0.f) || (y != 0.f) || (z != 0.f)) ? 1.f : 0.f;
        float dd = fminf(sqrtf(fmaxf(b0, 0.f)), 1e10f)
                 + fminf(sqrtf(fmaxf(b1, 0.f)), 1e10f)
                 + fminf(sqrtf(fmaxf(b2, 0.f)), 1e10f);
        dsum = dd * wcnt;
    }
    #pragma unroll
    for (int off = 32; off > 0; off >>= 1) {
        dsum += __shfl_down(dsum, off, 64);
        wcnt += __shfl_down(wcnt, off, 64);
    }
    if (lane == 0) { sd[wv] = dsum; sw4[wv] = wcnt; }
    __syncthreads();
    if (tid == 0) {
        atomicAdd(&accum[b * 2 + 0], sd[0] + sd[1] + sd[2] + sd[3]);
        atomicAdd(&accum[b * 2 + 1], sw4[0] + sw4[1] + sw4[2] + sw4[3]);
        __threadfence();
        int rr = atomicAdd(done_cnt, 1);
        if (rr == NB * 128 - 1) {
            float s0 = atomicAdd(&accum[0], 0.f);
            float cc0 = atomicAdd(&accum[1], 0.f);
            float s1 = atomicAdd(&accum[2], 0.f);
            float cc1 = atomicAdd(&accum[3], 0.f);
            out[0] = (s0 / (3.f * fmaxf(cc0, 1.f))
                    + s1 / (3.f * fmaxf(cc1, 1.f))) / (float)NB;
        }
    }
}

// ---------------------------------------------------------------------------
extern "C" void kernel_launch(void* const* d_in, const int* in_sizes, int n_in,
                              void* d_out, int out_size, void* d_ws, size_t ws_size,
                              hipStream_t stream) {
    const float* src_pc = (const float*)d_in[0];   // [2,64,2048,3]
    const float* tgt_pc = (const float*)d_in[1];   // [2,3,64,2048]
    float* out = (float*)d_out;

    char* ws = (char*)d_ws;
    float*  accum   = (float*)ws;                   // 16 B  @ 0
    int*    done    = (int*)(ws + 32);              // 4 B   @ 32
    int*    qtcnt   = (int*)(ws + 64);              // 1 KB  @ 64
    float*  partial = (float*)(ws + 4096);          // 24*NQT*4 = 3 MB
    uint4*  packed  = (uint4*)(ws + 4096 + 3145728);    // 1 MB
    float4* tgt4    = (float4*)(ws + 4096 + 4194304);   // 512 KB

    pack_kernel<<<NQT / 256, 256, 0, stream>>>(tgt_pc, packed, tgt4, (int*)ws);
    knn_mfma<<<NB * NCH * 128, 256, 0, stream>>>(src_pc, packed, tgt4, partial,
                                                 accum, qtcnt, done, out);
}

// Round 10
// 124.992 us; speedup vs baseline: 2.2329x; 2.2329x over previous
//
#include <hip/hip_runtime.h>
#include <math.h>

#define NB 2
#define NQ 16384        // 32*512 downsampled points per batch
#define IN_H 64
#define IN_W 2048
#define BIG 1e30f
#define NQT (NB * NQ)
#define NCH 8           // target chunks per batch
#define CHT 2048        // targets per chunk = 64 MFMA tiles
#define PLN ((size_t)IN_H * IN_W)

typedef __bf16 bf16x8 __attribute__((ext_vector_type(8)));
typedef float f32x16 __attribute__((ext_vector_type(16)));

__device__ inline float med3(float a, float b, float c) {
    return __builtin_amdgcn_fmed3f(a, b, c);
}
// branchless sorted-insert of v into b0<=b1<=b2 (3 VALU)
#define INSERT3(B0, B1, B2, V)                    \
    do { float _v = (V);                          \
         (B2) = med3((B1), (B2), _v);             \
         (B1) = med3((B0), (B1), _v);             \
         (B0) = fminf((B0), _v); } while (0)

union PK { __bf16 h[8]; uint4 u; };

// ---------------------------------------------------------------------------
// pack_kernel (R6-verified): (a) compensated bf16 A-fragments for
// mfma_f32_32x32x16_bf16 — lane holds A[row=lane&31][k=(lane>>5)*8+j];
// -2 folded into t, ||t||^2 hi/lo, BIG sentinel for invalid targets;
// (b) compact fp32 float4 (x,y,z,||t||^2) for the exact pass-2 recompute;
// (c) zeroes the control region (accum/done) — no memset node.
// ---------------------------------------------------------------------------
__global__ __launch_bounds__(256) void pack_kernel(
    const float* __restrict__ tgt_pc,   // [B,3,64,2048]
    uint4* __restrict__ packed,
    float4* __restrict__ tgt4,
    int* __restrict__ zws)              // control region
{
    if (blockIdx.x == 0 && threadIdx.x < 16) zws[threadIdx.x] = 0;

    int gid = blockIdx.x * 256 + threadIdx.x;   // [0, NB*NQ)
    int b = gid >> 14, t = gid & (NQ - 1);
    int oh = t >> 9, ow = t & 511;
    size_t base = ((size_t)(b * 3) * IN_H + oh * 2) * IN_W + ow * 4;
    float x = tgt_pc[base], y = tgt_pc[base + PLN], z = tgt_pc[base + 2 * PLN];
    bool valid = (x != 0.f) || (y != 0.f) || (z != 0.f);
    float ntx = x * x + y * y + z * z;
    float nt = valid ? ntx : BIG;               // pass-1 sentinel
    float tx = valid ? -2.f * x : 0.f;
    float ty = valid ? -2.f * y : 0.f;
    float tz = valid ? -2.f * z : 0.f;

    __bf16 txh = (__bf16)tx, tyh = (__bf16)ty, tzh = (__bf16)tz;
    __bf16 txl = (__bf16)(tx - (float)txh);
    __bf16 tyl = (__bf16)(ty - (float)tyh);
    __bf16 tzl = (__bf16)(tz - (float)tzh);
    __bf16 nth = (__bf16)nt;
    __bf16 ntl = (__bf16)(nt - (float)nth);

    PK h0, h1;
    h0.h[0] = txh; h0.h[1] = tyh; h0.h[2] = tzh; h0.h[3] = txh;
    h0.h[4] = tyh; h0.h[5] = tzh; h0.h[6] = txl; h0.h[7] = tyl;
    h1.h[0] = tzl; h1.h[1] = nth; h1.h[2] = ntl; h1.h[3] = (__bf16)1.0f;
    h1.h[4] = (__bf16)1.0f; h1.h[5] = (__bf16)0.0f;
    h1.h[6] = (__bf16)0.0f; h1.h[7] = (__bf16)0.0f;

    int tile = t >> 5, m = t & 31;
    size_t o = (size_t)(b * 512 + tile) * 64 + m;   // uint4 units
    packed[o]      = h0.u;   // k0..7
    packed[o + 32] = h1.u;   // k8..15

    tgt4[gid] = make_float4(valid ? x : 0.f, valid ? y : 0.f,
                            valid ? z : 0.f, valid ? ntx : 1e20f);
}

// ---------------------------------------------------------------------------
// knn_mfma: R9 body with phase-3 AMPUTATED (no __threadfence / atomics /
// winner merge — R7/R8/R9 all pinned at ~220 µs regardless of main-loop
// changes; the per-block device-scope fence (L2 writeback/invalidate on
// gfx950's non-coherent per-XCD L2s) was serializing the whole grid.
// Cross-block visibility is now provided by the inter-dispatch barrier.)
// block = 128 queries (4 waves x 32, query col = lane&31) x one 2048-target
// chunk (64 tiles). grid = NB*NCH*128 = 2048 blocks ~8/CU, 2x8KB LDS dbuf.
// Pass 1: per tile MFMA + min-tree(16) + idx-pack(6b) + INSERT3 -> top-3
//         candidate tiles/lane (top-3 values live in the 3 min-tiles).
// Pass 2: exact fp32 recompute of 3x16 candidate rows from tgt4 (L2).
// ---------------------------------------------------------------------------
__global__ __launch_bounds__(256) void knn_mfma(
    const float* __restrict__ src_pc,   // [B,64,2048,3]
    const uint4* __restrict__ packed,
    const float4* __restrict__ tgt4,
    float* __restrict__ partial)        // [NCH*3][NQT] plane-major
{
    __shared__ uint4 lds[2][512];       // 2 x 8 KB

    const int tid = threadIdx.x;
    const int lane = tid & 63;
    const int wv = tid >> 6;
    const int half = lane >> 5;
    const int blk = blockIdx.x;
    const int qt = blk & 127;                   // 128 query tiles of 128
    const int chunk = (blk >> 7) & (NCH - 1);
    const int b = blk >> 10;
    const int n = lane & 31;
    const int q = qt * 128 + wv * 32 + n;

    // ---- query-side B fragment (col = lane&31, k = (lane>>5)*8 + j) ----
    size_t sbase = (((size_t)b * IN_H + (q >> 9) * 2) * IN_W + (q & 511) * 4) * 3;
    float sx = src_pc[sbase], sy = src_pc[sbase + 1], sz = src_pc[sbase + 2];
    float ns = sx * sx + sy * sy + sz * sz;
    __bf16 sxh = (__bf16)sx, syh = (__bf16)sy, szh = (__bf16)sz;
    __bf16 sxl = (__bf16)(sx - (float)sxh);
    __bf16 syl = (__bf16)(sy - (float)syh);
    __bf16 szl = (__bf16)(sz - (float)szh);
    __bf16 nsh = (__bf16)ns, nsl = (__bf16)(ns - (float)nsh);
    bf16x8 bq;
    if (half == 0) {
        bq[0] = sxh; bq[1] = syh; bq[2] = szh; bq[3] = sxl;
        bq[4] = syl; bq[5] = szl; bq[6] = sxh; bq[7] = syh;
    } else {
        bq[0] = szh; bq[1] = (__bf16)1.0f; bq[2] = (__bf16)1.0f; bq[3] = nsh;
        bq[4] = nsl; bq[5] = (__bf16)0.0f; bq[6] = (__bf16)0.0f; bq[7] = (__bf16)0.0f;
    }

    f32x16 zero;
    #pragma unroll
    for (int i = 0; i < 16; ++i) zero[i] = 0.f;

    float c0 = BIG, c1 = BIG, c2 = BIG;     // packed (tile-min | tile-idx)

    // this chunk's 64 tiles, 64 uint4 each
    const uint4* pkq = packed + (size_t)b * 32768 + (size_t)chunk * 4096;

    uint4 r[2];
    #pragma unroll
    for (int i = 0; i < 2; ++i) r[i] = pkq[tid + 256 * i];          // stage 0
    #pragma unroll
    for (int i = 0; i < 2; ++i) lds[0][tid + 256 * i] = r[i];
    __syncthreads();

    for (int s = 0; s < 8; ++s) {
        uint4 rn[2];
        if (s < 7) {
            const uint4* nsrc = pkq + (s + 1) * 512;
            #pragma unroll
            for (int i = 0; i < 2; ++i) rn[i] = nsrc[tid + 256 * i];
        }
        const uint4* buf = lds[s & 1];
        #pragma unroll 2
        for (int t = 0; t < 8; ++t) {
            bf16x8 af = __builtin_bit_cast(bf16x8, buf[t * 64 + lane]);
            f32x16 d = __builtin_amdgcn_mfma_f32_32x32x16_bf16(af, bq, zero, 0, 0, 0);
            float m0 = fminf(fminf(d[0], d[1]), fminf(d[2], d[3]));
            float m1 = fminf(fminf(d[4], d[5]), fminf(d[6], d[7]));
            float m2 = fminf(fminf(d[8], d[9]), fminf(d[10], d[11]));
            float m3 = fminf(fminf(d[12], d[13]), fminf(d[14], d[15]));
            float mm = fminf(fminf(m0, m1), fminf(m2, m3));
            unsigned u = (__float_as_uint(mm) & ~63u) | (unsigned)(s * 8 + t);
            INSERT3(c0, c1, c2, __uint_as_float(u));
        }
        if (s < 7) {
            #pragma unroll
            for (int i = 0; i < 2; ++i) lds[1 - (s & 1)][tid + 256 * i] = rn[i];
        }
        __syncthreads();
    }

    // ---- pass 2: exact fp32 recompute of 3 candidate tiles from L2 ----
    int ti0 = (int)(__float_as_uint(c0) & 63u);
    int ti1 = (int)(__float_as_uint(c1) & 63u);
    int ti2 = (int)(__float_as_uint(c2) & 63u);
    float e0 = BIG, e1 = BIG, e2 = BIG;
    const float4* t4b = tgt4 + (size_t)b * NQ + (size_t)chunk * CHT;
    #pragma unroll
    for (int i = 0; i < 3; ++i) {
        int ct = (i == 0) ? ti0 : (i == 1) ? ti1 : ti2;
        int tbase = ct * 32 + 4 * half;
        #pragma unroll 4
        for (int rr = 0; rr < 16; ++rr) {
            int row = (rr & 3) + 8 * (rr >> 2);
            float4 tv = t4b[tbase + row];
            float dot = sx * tv.x;
            dot = fmaf(sy, tv.y, dot);
            dot = fmaf(sz, tv.z, dot);
            float d2 = fmaf(-2.f, dot, ns + tv.w);
            INSERT3(e0, e1, e2, d2);
        }
    }

    // ---- merge lane halves (L <- L+32, same query col), write planes ----
    float f0 = __shfl_down(e0, 32, 64);
    float f1 = __shfl_down(e1, 32, 64);
    float f2 = __shfl_down(e2, 32, 64);
    if (half == 0) {
        INSERT3(e0, e1, e2, f0);
        INSERT3(e0, e1, e2, f1);
        INSERT3(e0, e1, e2, f2);
        int gq = b * NQ + q;
        partial[(chunk * 3 + 0) * NQT + gq] = e0;
        partial[(chunk * 3 + 1) * NQT + gq] = e1;
        partial[(chunk * 3 + 2) * NQT + gq] = e2;
    }
}

// ---------------------------------------------------------------------------
// merge_final (R6-verified): per query merge NCH chunk-trios, sqrt+clamp,
// masked reduce, per-batch atomics; last finished block -> scalar output.
// (Its single tid==0 fence runs 128 times total, off the hot path.)
// ---------------------------------------------------------------------------
__global__ __launch_bounds__(256) void merge_final(
    const float* __restrict__ partial,
    const float* __restrict__ src_pc,
    float* __restrict__ accum,          // {sum0,cnt0,sum1,cnt1}
    int* __restrict__ done_cnt,
    float* __restrict__ out)
{
    int gid = blockIdx.x * 256 + threadIdx.x;   // < NQT
    int b = gid >> 14;
    int q = gid & (NQ - 1);

    float b0 = BIG, b1 = BIG, b2 = BIG;
    #pragma unroll
    for (int c = 0; c < NCH * 3; ++c) {
        float v = partial[c * NQT + gid];       // coalesced plane reads
        INSERT3(b0, b1, b2, v);
    }

    size_t base = (((size_t)b * IN_H + (q >> 9) * 2) * IN_W + (q & 511) * 4) * 3;
    float x = src_pc[base], y = src_pc[base + 1], z = src_pc[base + 2];
    float wt = ((x != 0.f) || (y != 0.f) || (z != 0.f)) ? 1.f : 0.f;

    float d = fminf(sqrtf(fmaxf(b0, 0.f)), 1e10f)
            + fminf(sqrtf(fmaxf(b1, 0.f)), 1e10f)
            + fminf(sqrtf(fmaxf(b2, 0.f)), 1e10f);
    float dsum = d * wt;

    #pragma unroll
    for (int off = 32; off > 0; off >>= 1) {
        dsum += __shfl_down(dsum, off, 64);
        wt   += __shfl_down(wt, off, 64);
    }
    __shared__ float sd[4], sw4[4];
    int lane = threadIdx.x & 63, wv = threadIdx.x >> 6;
    if (lane == 0) { sd[wv] = dsum; sw4[wv] = wt; }
    __syncthreads();
    if (threadIdx.x == 0) {
        atomicAdd(&accum[b * 2 + 0], sd[0] + sd[1] + sd[2] + sd[3]);
        atomicAdd(&accum[b * 2 + 1], sw4[0] + sw4[1] + sw4[2] + sw4[3]);
        __threadfence();
        int done = atomicAdd(done_cnt, 1);
        if (done == (int)gridDim.x - 1) {
            float s0 = atomicAdd(&accum[0], 0.f);
            float c0 = atomicAdd(&accum[1], 0.f);
            float s1 = atomicAdd(&accum[2], 0.f);
            float c1 = atomicAdd(&accum[3], 0.f);
            float r = s0 / (3.0f * fmaxf(c0, 1.0f))
                    + s1 / (3.0f * fmaxf(c1, 1.0f));
            out[0] = r / (float)NB;
        }
    }
}

// ---------------------------------------------------------------------------
extern "C" void kernel_launch(void* const* d_in, const int* in_sizes, int n_in,
                              void* d_out, int out_size, void* d_ws, size_t ws_size,
                              hipStream_t stream) {
    const float* src_pc = (const float*)d_in[0];   // [2,64,2048,3]
    const float* tgt_pc = (const float*)d_in[1];   // [2,3,64,2048]
    float* out = (float*)d_out;

    char* ws = (char*)d_ws;
    float*  accum   = (float*)ws;                   // 16 B  @ 0
    int*    done    = (int*)(ws + 32);              // 4 B   @ 32
    float*  partial = (float*)(ws + 4096);          // 24*NQT*4 = 3 MB
    uint4*  packed  = (uint4*)(ws + 4096 + 3145728);    // 1 MB
    float4* tgt4    = (float4*)(ws + 4096 + 4194304);   // 512 KB

    pack_kernel<<<NQT / 256, 256, 0, stream>>>(tgt_pc, packed, tgt4, (int*)ws);
    knn_mfma<<<NB * NCH * 128, 256, 0, stream>>>(src_pc, packed, tgt4, partial);
    merge_final<<<NQT / 256, 256, 0, stream>>>(partial, src_pc, accum, done, out);
}